// Round 4
// baseline (200.915 us; speedup 1.0000x reference)
//
#include <hip/hip_runtime.h>
#include <cstdint>
#include <cstddef>

#define Bsz 65536
#define Dsz 256
#define Fsz 512
#define Psz 256

typedef __attribute__((ext_vector_type(8))) short short8;
typedef __attribute__((ext_vector_type(4))) short short4v;
typedef __attribute__((ext_vector_type(4))) float float4v;
typedef __attribute__((ext_vector_type(16))) float float16v;
typedef __attribute__((ext_vector_type(4))) unsigned uint4v;

__device__ inline short f2bf(float f) {
    unsigned u = __builtin_bit_cast(unsigned, f);
    u = (u + 0x7FFFu + ((u >> 16) & 1u)) >> 16;   // RNE
    return (short)u;
}
__device__ inline float bf2f(short s) {
    unsigned u = ((unsigned)(unsigned short)s) << 16;
    return __builtin_bit_cast(float, u);
}
__device__ inline unsigned cvt_pk_bf16(float lo, float hi) {
    unsigned r;
    asm("v_cvt_pk_bf16_f32 %0, %1, %2" : "=v"(r) : "v"(lo), "v"(hi));
    return r;   // D[15:0]=bf16(lo), D[31:16]=bf16(hi), RNE
}
// async global->LDS, 16B per lane; lds dest wave-uniform base (HW adds lane*16)
__device__ inline void gl_lds16(const short* g, short* lds) {
    __builtin_amdgcn_global_load_lds((const __attribute__((address_space(1))) unsigned*)g,
                                     (__attribute__((address_space(3))) unsigned*)lds,
                                     16, 0, 0);
}

// ---------------------------------------------------------------------------
// Layouts (addresses in shorts):
//   featbB[((ft*16 + dt)*64 + lane)*8 + j] = bf16 features[32*ft + (lane&31)][16*dt + 8*(lane>>5) + j]
//     -> A-frag of mfma_32x32x16 (row=lane&31, k=8h+j) for chunk ft, d-tile dt.
//   pab[(((c*4 + s)*8 + pt)*512) + lane*8 + j] = pA[32*pt + (lane&31)][64*c + 16*s + 8*(lane>>5) + j]
//     where kappa = 2f+i :  pA[2f]   = theta*pw + alpha*(pp-1)
//                           pA[2f+1] = beta*pw          (pp=relu(pf), pw=pf*pp)
//     -> B-frag of mfma_32x32x16 (col=lane&31, k=8h+j).
//   pws_part[nc*256 + p] = -beta * sum_{f in nc-slice} pw[p][f]   (k_main sums the 4 parts)
// ---------------------------------------------------------------------------

#define SBPITCH 136

// ---------------- k_pre: merged features-convert + p-side GEMM (unchanged, verified) ----------------
__global__ __launch_bounds__(256, 2) void k_pre(
    const float* __restrict__ prototypes, const float* __restrict__ features,
    const float* __restrict__ alpha_p, const float* __restrict__ beta_p,
    const float* __restrict__ theta_p,
    short* __restrict__ featbB, short* __restrict__ pab, float* __restrict__ pws_part)
{
    __shared__ char lds[65536 + 17408];
    short* FB = (short*)lds;               // featb slice, frag order: [4 ftl][16 dt][64 lane][8]
    short* As = (short*)(lds + 65536);     // prototype staging (8 KB), XOR-swizzled
    short* Sb = (short*)(lds + 65536);     // epilogue bounce (after last As use)

    const int t = threadIdx.x;
    const int w = t >> 6, lane = t & 63, l15 = lane & 15, l4 = lane >> 4;
    const int rowg = blockIdx.x >> 2, nc = blockIdx.x & 3;
    const float alpha = *alpha_p, beta = *beta_p, theta = *theta_p;

    #pragma unroll
    for (int it = 0; it < 16; ++it) {
        int u = it * 256 + t;                       // 0..4095
        int ftl = u >> 10, dtl = (u >> 6) & 15, ln = u & 63;
        const float* src = features + (size_t)(nc * 128 + ftl * 32 + (ln & 31)) * Dsz
                         + dtl * 16 + (ln >> 5) * 8;
        float4v v0 = *(const float4v*)src;
        float4v v1 = *(const float4v*)(src + 4);
        uint4v uv;
        uv.x = cvt_pk_bf16(v0.x, v0.y);
        uv.y = cvt_pk_bf16(v0.z, v0.w);
        uv.z = cvt_pk_bf16(v1.x, v1.y);
        uv.w = cvt_pk_bf16(v1.z, v1.w);
        short8 sv = __builtin_bit_cast(short8, uv);
        *(short8*)&FB[u * 8] = sv;
        if (rowg == 0) {
            int go = (((nc * 4 + ftl) * 16 + dtl) * 64 + ln) * 8;
            *(short8*)&featbB[go] = sv;
        }
    }

    float4v acc[2][4];
    #pragma unroll
    for (int a = 0; a < 2; ++a)
        #pragma unroll
        for (int b = 0; b < 4; ++b) acc[a][b] = (float4v){0.f, 0.f, 0.f, 0.f};

    const float* pbase = prototypes + (size_t)rowg * 64 * Dsz;

    for (int kc = 0; kc < 4; ++kc) {
        __syncthreads();
        #pragma unroll
        for (int j = 0; j < 4; ++j) {
            int idx = j * 1024 + t * 4;
            int r = idx >> 6, c = idx & 63;
            float4v v = *(const float4v*)(pbase + (size_t)r * Dsz + kc * 64 + c);
            int unit = r * 8 + ((c >> 3) ^ (r & 7));
            short4v s4; s4.x = f2bf(v.x); s4.y = f2bf(v.y); s4.z = f2bf(v.z); s4.w = f2bf(v.w);
            *(short4v*)((char*)As + unit * 16 + (c & 7) * 2) = s4;
        }
        __syncthreads();
        #pragma unroll
        for (int kk = 0; kk < 2; ++kk) {
            short8 af[2], bfr[4];
            const int k8 = kk * 4 + l4;
            #pragma unroll
            for (int tm = 0; tm < 2; ++tm) {
                int m = (w & 1) * 32 + tm * 16 + l15;
                af[tm] = *(const short8*)&As[(m * 8 + (k8 ^ (m & 7))) * 8];
            }
            #pragma unroll
            for (int tn = 0; tn < 4; ++tn) {
                int fl = ((w >> 1) * 4 + tn) * 16 + l15;          // 0..127
                int dtl = kc * 4 + kk * 2 + (l4 >> 1);
                int lnp = (fl & 31) + 32 * (l4 & 1);
                bfr[tn] = *(const short8*)&FB[(((fl >> 5) * 16 + dtl) * 64 + lnp) * 8];
            }
            #pragma unroll
            for (int tm = 0; tm < 2; ++tm)
                #pragma unroll
                for (int tn = 0; tn < 4; ++tn)
                    acc[tm][tn] = __builtin_amdgcn_mfma_f32_16x16x32_bf16(af[tm], bfr[tn], acc[tm][tn], 0, 0, 0);
        }
    }
    __syncthreads();
    #pragma unroll
    for (int tm = 0; tm < 2; ++tm)
        #pragma unroll
        for (int tn = 0; tn < 4; ++tn)
            #pragma unroll
            for (int r = 0; r < 4; ++r) {
                int row = (w & 1) * 32 + tm * 16 + l4 * 4 + r;
                int col = (w >> 1) * 64 + tn * 16 + l15;
                Sb[row * SBPITCH + col] = f2bf(acc[tm][tn][r]);
            }
    __syncthreads();
    #pragma unroll
    for (int rep = 0; rep < 4; ++rep) {
        int u = rep * 256 + t;
        int row = u >> 4, i = u & 15;
        short8 sv = *(const short8*)&Sb[row * SBPITCH + i * 8];
        uint4v u0, u1;
        float sum = 0.f;
        #pragma unroll
        for (int e = 0; e < 8; ++e) {
            float pf = bf2f(sv[e]);
            float pp = fmaxf(pf, 0.f);
            float pw = pf * pp;
            float a0 = theta * pw + alpha * (pp - 1.f);   // multiplies xw
            float b0 = beta * pw;                          // multiplies xp
            sum += pw;
            unsigned pk = cvt_pk_bf16(a0, b0);
            if (e < 4) u0[e] = pk; else u1[e - 4] = pk;
        }
        int p = rowg * 64 + row;
        int c = 4 * nc + (i >> 2), s2 = i & 3, pt = p >> 5;
        int base = ((c * 4 + s2) * 8 + pt) * 512;
        *(short8*)&pab[base + (p & 31) * 8] = __builtin_bit_cast(short8, u0);
        *(short8*)&pab[base + ((p & 31) + 32) * 8] = __builtin_bit_cast(short8, u1);
        #pragma unroll
        for (int mk = 1; mk < 16; mk <<= 1) sum += __shfl_xor(sum, mk, 64);
        if (l15 == 0) pws_part[nc * 256 + p] = -beta * sum;
    }
}

// ---------------- k_main: 2-chunk software pipeline (stage2(c-1) interleaved with stage1(c)) ----------------
// 512 blocks x 512 thr. Block: 128 m x 256 p. Wave: mt=w&3 (32 rows), pth=w>>2 (128 p).
// FBL double-buffered (2x16KB), PBL triple-buffered (3x32KB) so chunk c-1's p-frags stay live
// while chunk c+1 stages. One barrier per chunk; gl_lds issued right after it (full-body slack).
__global__ __launch_bounds__(512, 2) void k_main(
    const float* __restrict__ x, const short* __restrict__ featbB,
    const short* __restrict__ pab, const float* __restrict__ pws_part,
    float* __restrict__ out)
{
    __shared__ short FBL[2 * 8192];     // fb dbuf: [buf][16 dt][lane*8]
    __shared__ short PBL[3 * 16384];    // pab tbuf: [buf][32 tiles][lane*8]

    const int t = threadIdx.x;
    const int w = t >> 6, lane = t & 63, l31 = lane & 31, h = lane >> 5;
    const int mt = w & 3, pth4 = (w >> 2) * 4;
    const size_t row0 = (size_t)blockIdx.x * 128;
    const int lane8 = lane * 8;

    // staging helper: chunk cn -> FBL[foff], PBL[poff]
    auto stage = [&](int cn, int foff, int poff) {
        const short* fsrc = featbB + cn * 8192 + lane8;
        gl_lds16(fsrc + (2 * w) * 512,     &FBL[foff + (2 * w) * 512]);
        gl_lds16(fsrc + (2 * w + 1) * 512, &FBL[foff + (2 * w + 1) * 512]);
        const short* psrc = pab + cn * 16384 + lane8;
        #pragma unroll
        for (int i = 0; i < 4; ++i)
            gl_lds16(psrc + (4 * w + i) * 512, &PBL[poff + (4 * w + i) * 512]);
    };

    // ---- prologue: stage chunk 0; x -> 16 register frags while it flies ----
    stage(0, 0, 0);
    __builtin_amdgcn_sched_barrier(0);

    short8 xf[16];
    {
        const float* xr = x + (row0 + mt * 32 + l31) * Dsz + h * 8;
        #pragma unroll
        for (int dt = 0; dt < 16; ++dt) {
            float4v v0 = *(const float4v*)(xr + dt * 16);
            float4v v1 = *(const float4v*)(xr + dt * 16 + 4);
            uint4v uv;
            uv.x = cvt_pk_bf16(v0.x, v0.y);
            uv.y = cvt_pk_bf16(v0.z, v0.w);
            uv.z = cvt_pk_bf16(v1.x, v1.y);
            uv.w = cvt_pk_bf16(v1.z, v1.w);
            xf[dt] = __builtin_bit_cast(short8, uv);
        }
    }

    float16v acc[4];
    #pragma unroll
    for (int a = 0; a < 4; ++a)
        #pragma unroll
        for (int e = 0; e < 16; ++e) acc[a][e] = 0.f;

    __syncthreads();                       // chunk-0 buffers ready
    stage(1, 8192, 16384);                 // chunk 1 -> FBL[1], PBL[1]
    __builtin_amdgcn_sched_barrier(0);

    // ---- stage-1(0) alone -> C1p (two interleaved chains, merged) ----
    float16v C1p;
    {
        float16v Ca, Cb;
        #pragma unroll
        for (int e = 0; e < 16; ++e) { Ca[e] = 0.f; Cb[e] = 0.f; }
        #pragma unroll
        for (int g = 0; g < 4; ++g) {
            short8 fbf[4];
            #pragma unroll
            for (int i = 0; i < 4; ++i)
                fbf[i] = *(const short8*)&FBL[(g * 4 + i) * 512 + lane8];
            __builtin_amdgcn_s_setprio(1);
            #pragma unroll
            for (int i = 0; i < 4; ++i) {
                if (i & 1) Cb = __builtin_amdgcn_mfma_f32_32x32x16_bf16(fbf[i], xf[g * 4 + i], Cb, 0, 0, 0);
                else       Ca = __builtin_amdgcn_mfma_f32_32x32x16_bf16(fbf[i], xf[g * 4 + i], Ca, 0, 0, 0);
            }
            __builtin_amdgcn_s_setprio(0);
        }
        #pragma unroll
        for (int e = 0; e < 16; ++e) C1p[e] = Ca[e] + Cb[e];
    }

    // ---- main loop: c = 1..15; body = stage2(c-1) interleaved with stage1(c) ----
    int pb_prev = 0, pb_cur = 16384, pb_nxt = 32768;
    #pragma unroll 1
    for (int c = 1; c < 16; ++c) {
        const int fcur = (c & 1) * 8192;

        __syncthreads();                   // FBL[fcur], PBL[pb_cur] landed (staged last iter)

        if (c < 15) stage(c + 1, fcur ^ 8192, pb_nxt);
        __builtin_amdgcn_sched_barrier(0); // pin staging at body top (keep its slack)

        float16v Ca, Cb;
        #pragma unroll
        for (int e = 0; e < 16; ++e) { Ca[e] = 0.f; Cb[e] = 0.f; }

        #pragma unroll
        for (int g = 0; g < 4; ++g) {
            // A-stream reads: fb frags of chunk c
            short8 fbf[4];
            #pragma unroll
            for (int i = 0; i < 4; ++i)
                fbf[i] = *(const short8*)&FBL[fcur + (g * 4 + i) * 512 + lane8];
            // B-stream reads: p frags of chunk c-1 (s = g)
            short8 PBr[4];
            #pragma unroll
            for (int ptl = 0; ptl < 4; ++ptl)
                PBr[ptl] = *(const short8*)&PBL[pb_prev + (g * 8 + pth4 + ptl) * 512 + lane8];
            // B-stream repack: operands in regs, no memory wait
            uint4v uf;
            #pragma unroll
            for (int q = 0; q < 4; ++q) {
                float xv = C1p[4 * g + q];
                float xp = fmaxf(xv, 0.f);
                uf[q] = cvt_pk_bf16(xv * xp, xp);   // kappa even: xw, kappa odd: xp
            }
            short8 A2f = __builtin_bit_cast(short8, uf);
            // B-stream MFMA (waits PBr; fbf returned in-order before it)
            __builtin_amdgcn_s_setprio(1);
            #pragma unroll
            for (int ptl = 0; ptl < 4; ++ptl)
                acc[ptl] = __builtin_amdgcn_mfma_f32_32x32x16_bf16(A2f, PBr[ptl], acc[ptl], 0, 0, 0);
            // A-stream MFMA (operands already landed)
            #pragma unroll
            for (int i = 0; i < 4; ++i) {
                if (i & 1) Cb = __builtin_amdgcn_mfma_f32_32x32x16_bf16(fbf[i], xf[g * 4 + i], Cb, 0, 0, 0);
                else       Ca = __builtin_amdgcn_mfma_f32_32x32x16_bf16(fbf[i], xf[g * 4 + i], Ca, 0, 0, 0);
            }
            __builtin_amdgcn_s_setprio(0);
        }
        #pragma unroll
        for (int e = 0; e < 16; ++e) C1p[e] = Ca[e] + Cb[e];

        int tmp = pb_prev; pb_prev = pb_cur; pb_cur = pb_nxt; pb_nxt = tmp;
    }

    // ---- tail: stage-2(15) from PBL[pb_prev] ----
    #pragma unroll
    for (int s = 0; s < 4; ++s) {
        short8 PBr[4];
        #pragma unroll
        for (int ptl = 0; ptl < 4; ++ptl)
            PBr[ptl] = *(const short8*)&PBL[pb_prev + (s * 8 + pth4 + ptl) * 512 + lane8];
        uint4v uf;
        #pragma unroll
        for (int q = 0; q < 4; ++q) {
            float xv = C1p[4 * s + q];
            float xp = fmaxf(xv, 0.f);
            uf[q] = cvt_pk_bf16(xv * xp, xp);
        }
        short8 A2f = __builtin_bit_cast(short8, uf);
        #pragma unroll
        for (int ptl = 0; ptl < 4; ++ptl)
            acc[ptl] = __builtin_amdgcn_mfma_f32_32x32x16_bf16(A2f, PBr[ptl], acc[ptl], 0, 0, 0);
    }

    // ---- epilogue: out[m][p] coalesced (p on lanes), + summed pws partials ----
    #pragma unroll
    for (int ptl = 0; ptl < 4; ++ptl) {
        int pcol = (pth4 + ptl) * 32 + l31;
        float pn = pws_part[pcol] + pws_part[256 + pcol] + pws_part[512 + pcol] + pws_part[768 + pcol];
        #pragma unroll
        for (int r = 0; r < 16; ++r) {
            size_t m = row0 + mt * 32 + (r & 3) + 8 * (r >> 2) + 4 * h;
            out[m * Psz + pcol] = acc[ptl][r] + pn;
        }
    }
}

// ---------------- launcher ----------------
extern "C" void kernel_launch(void* const* d_in, const int* in_sizes, int n_in,
                              void* d_out, int out_size, void* d_ws, size_t ws_size,
                              hipStream_t stream) {
    const float* x          = (const float*)d_in[0];
    const float* features   = (const float*)d_in[1];
    const float* prototypes = (const float*)d_in[2];
    const float* alpha      = (const float*)d_in[3];
    const float* beta       = (const float*)d_in[4];
    const float* theta      = (const float*)d_in[5];
    float* out = (float*)d_out;

    // ws: featbB 256KB @0, pab 512KB @262144, pws_part 4KB @786432
    char* ws = (char*)d_ws;
    short* featbB   = (short*)(ws);
    short* pab      = (short*)(ws + 262144);
    float* pws_part = (float*)(ws + 786432);

    hipLaunchKernelGGL(k_pre,  dim3(16),  dim3(256), 0, stream,
                       prototypes, features, alpha, beta, theta, featbB, pab, pws_part);
    hipLaunchKernelGGL(k_main, dim3(512), dim3(512), 0, stream,
                       x, featbB, pab, pws_part, out);
}

// Round 5
// 188.842 us; speedup vs baseline: 1.0639x; 1.0639x over previous
//
#include <hip/hip_runtime.h>
#include <cstdint>
#include <cstddef>

#define Bsz 65536
#define Dsz 256
#define Fsz 512
#define Psz 256

typedef __attribute__((ext_vector_type(8))) short short8;
typedef __attribute__((ext_vector_type(4))) short short4v;
typedef __attribute__((ext_vector_type(4))) float float4v;
typedef __attribute__((ext_vector_type(16))) float float16v;
typedef __attribute__((ext_vector_type(4))) unsigned uint4v;

__device__ inline short f2bf(float f) {
    unsigned u = __builtin_bit_cast(unsigned, f);
    u = (u + 0x7FFFu + ((u >> 16) & 1u)) >> 16;   // RNE
    return (short)u;
}
__device__ inline float bf2f(short s) {
    unsigned u = ((unsigned)(unsigned short)s) << 16;
    return __builtin_bit_cast(float, u);
}
__device__ inline unsigned cvt_pk_bf16(float lo, float hi) {
    unsigned r;
    asm("v_cvt_pk_bf16_f32 %0, %1, %2" : "=v"(r) : "v"(lo), "v"(hi));
    return r;   // D[15:0]=bf16(lo), D[31:16]=bf16(hi), RNE
}
// async global->LDS, 16B per lane; lds dest wave-uniform base (HW adds lane*16)
__device__ inline void gl_lds16(const short* g, short* lds) {
    __builtin_amdgcn_global_load_lds((const __attribute__((address_space(1))) unsigned*)g,
                                     (__attribute__((address_space(3))) unsigned*)lds,
                                     16, 0, 0);
}

// ---------------------------------------------------------------------------
// Layouts (addresses in shorts):
//   featbB[((ft*16 + dt)*64 + lane)*8 + j] = bf16 features[32*ft + (lane&31)][16*dt + 8*(lane>>5) + j]
//     -> A-frag of mfma_32x32x16 (row=lane&31, k=8h+j) for chunk ft, d-tile dt.
//   pab[(((c*4 + s)*8 + pt)*512) + lane*8 + j] = pA[32*pt + (lane&31)][64*c + 16*s + 8*(lane>>5) + j]
//     where kappa = 2f+i :  pA[2f]   = theta*pw + alpha*(pp-1)
//                           pA[2f+1] = beta*pw          (pp=relu(pf), pw=pf*pp)
//     -> B-frag of mfma_32x32x16 (col=lane&31, k=8h+j).
//   pws_part[nc*256 + p] = -beta * sum_{f in nc-slice} pw[p][f]   (k_main sums the 4 parts)
// ---------------------------------------------------------------------------

#define SBPITCH 136

// ---------------- k_pre: merged features-convert + p-side GEMM (unchanged, verified) ----------------
__global__ __launch_bounds__(256, 2) void k_pre(
    const float* __restrict__ prototypes, const float* __restrict__ features,
    const float* __restrict__ alpha_p, const float* __restrict__ beta_p,
    const float* __restrict__ theta_p,
    short* __restrict__ featbB, short* __restrict__ pab, float* __restrict__ pws_part)
{
    __shared__ char lds[65536 + 17408];
    short* FB = (short*)lds;               // featb slice, frag order: [4 ftl][16 dt][64 lane][8]
    short* As = (short*)(lds + 65536);     // prototype staging (8 KB), XOR-swizzled
    short* Sb = (short*)(lds + 65536);     // epilogue bounce (after last As use)

    const int t = threadIdx.x;
    const int w = t >> 6, lane = t & 63, l15 = lane & 15, l4 = lane >> 4;
    const int rowg = blockIdx.x >> 2, nc = blockIdx.x & 3;
    const float alpha = *alpha_p, beta = *beta_p, theta = *theta_p;

    #pragma unroll
    for (int it = 0; it < 16; ++it) {
        int u = it * 256 + t;                       // 0..4095
        int ftl = u >> 10, dtl = (u >> 6) & 15, ln = u & 63;
        const float* src = features + (size_t)(nc * 128 + ftl * 32 + (ln & 31)) * Dsz
                         + dtl * 16 + (ln >> 5) * 8;
        float4v v0 = *(const float4v*)src;
        float4v v1 = *(const float4v*)(src + 4);
        uint4v uv;
        uv.x = cvt_pk_bf16(v0.x, v0.y);
        uv.y = cvt_pk_bf16(v0.z, v0.w);
        uv.z = cvt_pk_bf16(v1.x, v1.y);
        uv.w = cvt_pk_bf16(v1.z, v1.w);
        short8 sv = __builtin_bit_cast(short8, uv);
        *(short8*)&FB[u * 8] = sv;
        if (rowg == 0) {
            int go = (((nc * 4 + ftl) * 16 + dtl) * 64 + ln) * 8;
            *(short8*)&featbB[go] = sv;
        }
    }

    float4v acc[2][4];
    #pragma unroll
    for (int a = 0; a < 2; ++a)
        #pragma unroll
        for (int b = 0; b < 4; ++b) acc[a][b] = (float4v){0.f, 0.f, 0.f, 0.f};

    const float* pbase = prototypes + (size_t)rowg * 64 * Dsz;

    for (int kc = 0; kc < 4; ++kc) {
        __syncthreads();
        #pragma unroll
        for (int j = 0; j < 4; ++j) {
            int idx = j * 1024 + t * 4;
            int r = idx >> 6, c = idx & 63;
            float4v v = *(const float4v*)(pbase + (size_t)r * Dsz + kc * 64 + c);
            int unit = r * 8 + ((c >> 3) ^ (r & 7));
            short4v s4; s4.x = f2bf(v.x); s4.y = f2bf(v.y); s4.z = f2bf(v.z); s4.w = f2bf(v.w);
            *(short4v*)((char*)As + unit * 16 + (c & 7) * 2) = s4;
        }
        __syncthreads();
        #pragma unroll
        for (int kk = 0; kk < 2; ++kk) {
            short8 af[2], bfr[4];
            const int k8 = kk * 4 + l4;
            #pragma unroll
            for (int tm = 0; tm < 2; ++tm) {
                int m = (w & 1) * 32 + tm * 16 + l15;
                af[tm] = *(const short8*)&As[(m * 8 + (k8 ^ (m & 7))) * 8];
            }
            #pragma unroll
            for (int tn = 0; tn < 4; ++tn) {
                int fl = ((w >> 1) * 4 + tn) * 16 + l15;          // 0..127
                int dtl = kc * 4 + kk * 2 + (l4 >> 1);
                int lnp = (fl & 31) + 32 * (l4 & 1);
                bfr[tn] = *(const short8*)&FB[(((fl >> 5) * 16 + dtl) * 64 + lnp) * 8];
            }
            #pragma unroll
            for (int tm = 0; tm < 2; ++tm)
                #pragma unroll
                for (int tn = 0; tn < 4; ++tn)
                    acc[tm][tn] = __builtin_amdgcn_mfma_f32_16x16x32_bf16(af[tm], bfr[tn], acc[tm][tn], 0, 0, 0);
        }
    }
    __syncthreads();
    #pragma unroll
    for (int tm = 0; tm < 2; ++tm)
        #pragma unroll
        for (int tn = 0; tn < 4; ++tn)
            #pragma unroll
            for (int r = 0; r < 4; ++r) {
                int row = (w & 1) * 32 + tm * 16 + l4 * 4 + r;
                int col = (w >> 1) * 64 + tn * 16 + l15;
                Sb[row * SBPITCH + col] = f2bf(acc[tm][tn][r]);
            }
    __syncthreads();
    #pragma unroll
    for (int rep = 0; rep < 4; ++rep) {
        int u = rep * 256 + t;
        int row = u >> 4, i = u & 15;
        short8 sv = *(const short8*)&Sb[row * SBPITCH + i * 8];
        uint4v u0, u1;
        float sum = 0.f;
        #pragma unroll
        for (int e = 0; e < 8; ++e) {
            float pf = bf2f(sv[e]);
            float pp = fmaxf(pf, 0.f);
            float pw = pf * pp;
            float a0 = theta * pw + alpha * (pp - 1.f);   // multiplies xw
            float b0 = beta * pw;                          // multiplies xp
            sum += pw;
            unsigned pk = cvt_pk_bf16(a0, b0);
            if (e < 4) u0[e] = pk; else u1[e - 4] = pk;
        }
        int p = rowg * 64 + row;
        int c = 4 * nc + (i >> 2), s2 = i & 3, pt = p >> 5;
        int base = ((c * 4 + s2) * 8 + pt) * 512;
        *(short8*)&pab[base + (p & 31) * 8] = __builtin_bit_cast(short8, u0);
        *(short8*)&pab[base + ((p & 31) + 32) * 8] = __builtin_bit_cast(short8, u1);
        #pragma unroll
        for (int mk = 1; mk < 16; mk <<= 1) sum += __shfl_xor(sum, mk, 64);
        if (l15 == 0) pws_part[nc * 256 + p] = -beta * sum;
    }
}

// ---------------- k_main: R0 decorrelation + m97 2-barrier staging ----------------
// 1024 blocks x 256 thr (4 waves), 2 blocks/CU. Block: 64 m x 256 p.
// Wave: mt=w&1 (32 rows), pth=w>>1 (128 p). x in regs (64 VGPR).
// Per chunk: [barrier A] issue pab(c)+fb(c+1) -> stage-1 (slack) -> [barrier B] -> stage-2.
// FBL dbuf 2x16KB, PBL single 32KB; LDS = 64KB exactly -> 2 blocks/CU.
__global__ __launch_bounds__(256, 2) void k_main(
    const float* __restrict__ x, const short* __restrict__ featbB,
    const short* __restrict__ pab, const float* __restrict__ pws_part,
    float* __restrict__ out)
{
    __shared__ short FBL[2][8192];   // fb dbuf: [buf][16 dt][lane*8]
    __shared__ short PBL[16384];     // pab single buf: [32 tiles][lane*8]

    const int t = threadIdx.x;
    const int w = t >> 6, lane = t & 63, l31 = lane & 31, h = lane >> 5;
    const int mt = w & 1, pth = w >> 1;
    const size_t row0 = (size_t)blockIdx.x * 64;
    const int lane8 = lane * 8;

    // fb chunk cn -> FBL[buf] (4 gl_lds per wave: tiles 4w..4w+3)
    auto stage_fb = [&](int cn, int buf) {
        const short* src = featbB + cn * 8192 + lane8;
        #pragma unroll
        for (int i = 0; i < 4; ++i)
            gl_lds16(src + (4 * w + i) * 512, &FBL[buf][(4 * w + i) * 512]);
    };
    // pab chunk cn -> PBL (8 gl_lds per wave: tiles 8w..8w+7)
    auto stage_pab = [&](int cn) {
        const short* src = pab + (size_t)cn * 16384 + lane8;
        #pragma unroll
        for (int i = 0; i < 8; ++i)
            gl_lds16(src + (8 * w + i) * 512, &PBL[(8 * w + i) * 512]);
    };

    // ---- prologue: issue chunk-0 staging; convert x to 16 register frags meanwhile ----
    stage_fb(0, 0);
    stage_pab(0);
    __builtin_amdgcn_sched_barrier(0);

    short8 xf[16];
    {
        const float* xr = x + (row0 + mt * 32 + l31) * Dsz + h * 8;
        #pragma unroll
        for (int dt = 0; dt < 16; ++dt) {
            float4v v0 = *(const float4v*)(xr + dt * 16);
            float4v v1 = *(const float4v*)(xr + dt * 16 + 4);
            uint4v uv;
            uv.x = cvt_pk_bf16(v0.x, v0.y);
            uv.y = cvt_pk_bf16(v0.z, v0.w);
            uv.z = cvt_pk_bf16(v1.x, v1.y);
            uv.w = cvt_pk_bf16(v1.z, v1.w);
            xf[dt] = __builtin_bit_cast(short8, uv);
        }
    }

    float16v acc[4];
    #pragma unroll
    for (int a = 0; a < 4; ++a)
        #pragma unroll
        for (int e = 0; e < 16; ++e) acc[a][e] = 0.f;

    __syncthreads();                         // chunk-0 fb + pab staged

    #pragma unroll 1
    for (int c = 0; c < 16; ++c) {
        const int cur = c & 1;

        if (c) {
            __syncthreads();                 // A: all waves done reading PBL (chunk c-1)
            stage_pab(c);                    // overwrite PBL with chunk c
        }
        if (c < 15) stage_fb(c + 1, cur ^ 1);
        __builtin_amdgcn_sched_barrier(0);   // pin staging issue before stage-1

        // ---- stage-1: C1[f][m] over K=256; fb from FBL[cur] (ready), x in regs ----
        float16v Ca, Cb;
        #pragma unroll
        for (int e = 0; e < 16; ++e) { Ca[e] = 0.f; Cb[e] = 0.f; }
        #pragma unroll
        for (int g = 0; g < 4; ++g) {
            short8 fbf[4];
            #pragma unroll
            for (int i = 0; i < 4; ++i)
                fbf[i] = *(const short8*)&FBL[cur][(g * 4 + i) * 512 + lane8];
            __builtin_amdgcn_s_setprio(1);
            #pragma unroll
            for (int i = 0; i < 4; ++i) {
                if (i & 1) Cb = __builtin_amdgcn_mfma_f32_32x32x16_bf16(fbf[i], xf[g * 4 + i], Cb, 0, 0, 0);
                else       Ca = __builtin_amdgcn_mfma_f32_32x32x16_bf16(fbf[i], xf[g * 4 + i], Ca, 0, 0, 0);
            }
            __builtin_amdgcn_s_setprio(0);
        }
        float16v C1;
        #pragma unroll
        for (int e = 0; e < 16; ++e) C1[e] = Ca[e] + Cb[e];

        __syncthreads();                     // B: PBL(c) + FBL(c+1) landed (drain covered by stage-1)

        // ---- stage-2: per s repack C1 -> A2 frag, 4 MFMA into acc; pb from PBL ----
        #pragma unroll
        for (int s = 0; s < 4; ++s) {
            short8 PBr[4];
            #pragma unroll
            for (int ptl = 0; ptl < 4; ++ptl)
                PBr[ptl] = *(const short8*)&PBL[(s * 8 + pth * 4 + ptl) * 512 + lane8];
            uint4v uf;
            #pragma unroll
            for (int q = 0; q < 4; ++q) {
                float xv = C1[4 * s + q];
                float xp = fmaxf(xv, 0.f);
                uf[q] = cvt_pk_bf16(xv * xp, xp);   // kappa even: xw, kappa odd: xp
            }
            short8 A2f = __builtin_bit_cast(short8, uf);
            __builtin_amdgcn_s_setprio(1);
            #pragma unroll
            for (int ptl = 0; ptl < 4; ++ptl)
                acc[ptl] = __builtin_amdgcn_mfma_f32_32x32x16_bf16(A2f, PBr[ptl], acc[ptl], 0, 0, 0);
            __builtin_amdgcn_s_setprio(0);
        }
    }

    // ---- epilogue: out[m][p] coalesced (p on lanes), + summed pws partials ----
    #pragma unroll
    for (int ptl = 0; ptl < 4; ++ptl) {
        int pcol = (pth * 4 + ptl) * 32 + l31;
        float pn = pws_part[pcol] + pws_part[256 + pcol] + pws_part[512 + pcol] + pws_part[768 + pcol];
        #pragma unroll
        for (int r = 0; r < 16; ++r) {
            size_t m = row0 + mt * 32 + (r & 3) + 8 * (r >> 2) + 4 * h;
            out[m * Psz + pcol] = acc[ptl][r] + pn;
        }
    }
}

// ---------------- launcher ----------------
extern "C" void kernel_launch(void* const* d_in, const int* in_sizes, int n_in,
                              void* d_out, int out_size, void* d_ws, size_t ws_size,
                              hipStream_t stream) {
    const float* x          = (const float*)d_in[0];
    const float* features   = (const float*)d_in[1];
    const float* prototypes = (const float*)d_in[2];
    const float* alpha      = (const float*)d_in[3];
    const float* beta       = (const float*)d_in[4];
    const float* theta      = (const float*)d_in[5];
    float* out = (float*)d_out;

    // ws: featbB 256KB @0, pab 512KB @262144, pws_part 4KB @786432
    char* ws = (char*)d_ws;
    short* featbB   = (short*)(ws);
    short* pab      = (short*)(ws + 262144);
    float* pws_part = (float*)(ws + 786432);

    hipLaunchKernelGGL(k_pre,  dim3(16),   dim3(256), 0, stream,
                       prototypes, features, alpha, beta, theta, featbB, pab, pws_part);
    hipLaunchKernelGGL(k_main, dim3(1024), dim3(256), 0, stream,
                       x, featbB, pab, pws_part, out);
}

// Round 6
// 180.418 us; speedup vs baseline: 1.1136x; 1.0467x over previous
//
#include <hip/hip_runtime.h>
#include <cstdint>
#include <cstddef>

#define Bsz 65536
#define Dsz 256
#define Fsz 512
#define Psz 256

typedef __attribute__((ext_vector_type(8))) short short8;
typedef __attribute__((ext_vector_type(4))) short short4v;
typedef __attribute__((ext_vector_type(4))) float float4v;
typedef __attribute__((ext_vector_type(16))) float float16v;
typedef __attribute__((ext_vector_type(4))) unsigned uint4v;

__device__ inline short f2bf(float f) {
    unsigned u = __builtin_bit_cast(unsigned, f);
    u = (u + 0x7FFFu + ((u >> 16) & 1u)) >> 16;   // RNE
    return (short)u;
}
__device__ inline float bf2f(short s) {
    unsigned u = ((unsigned)(unsigned short)s) << 16;
    return __builtin_bit_cast(float, u);
}
__device__ inline unsigned cvt_pk_bf16(float lo, float hi) {
    unsigned r;
    asm("v_cvt_pk_bf16_f32 %0, %1, %2" : "=v"(r) : "v"(lo), "v"(hi));
    return r;   // D[15:0]=bf16(lo), D[31:16]=bf16(hi), RNE
}
// async global->LDS, 16B per lane; lds dest wave-uniform base (HW adds lane*16)
__device__ inline void gl_lds16(const short* g, short* lds) {
    __builtin_amdgcn_global_load_lds((const __attribute__((address_space(1))) unsigned*)g,
                                     (__attribute__((address_space(3))) unsigned*)lds,
                                     16, 0, 0);
}

// ---------------------------------------------------------------------------
// Layouts (addresses in shorts):
//   featbB[((ft*16 + dt)*64 + lane)*8 + j] = bf16 features[32*ft + (lane&31)][16*dt + 8*(lane>>5) + j]
//     -> A-frag of mfma_32x32x16 (row=lane&31, k=8h+j) for chunk ft, d-tile dt.
//   pab[(((c*4 + s)*8 + pt)*512) + lane*8 + j] = pA[32*pt + (lane&31)][64*c + 16*s + 8*(lane>>5) + j]
//     where kappa = 2f+i :  pA[2f]   = theta*pw + alpha*(pp-1)
//                           pA[2f+1] = beta*pw          (pp=relu(pf), pw=pf*pp)
//     -> B-frag of mfma_32x32x16 (col=lane&31, k=8h+j).
//   pws_part[nc*256 + p] = -beta * sum_{f in nc-slice} pw[p][f]   (k_main sums the 4 parts)
// ---------------------------------------------------------------------------

#define SBPITCH 136

// ---------------- k_pre: merged features-convert + p-side GEMM (unchanged, verified) ----------------
__global__ __launch_bounds__(256, 2) void k_pre(
    const float* __restrict__ prototypes, const float* __restrict__ features,
    const float* __restrict__ alpha_p, const float* __restrict__ beta_p,
    const float* __restrict__ theta_p,
    short* __restrict__ featbB, short* __restrict__ pab, float* __restrict__ pws_part)
{
    __shared__ char lds[65536 + 17408];
    short* FB = (short*)lds;               // featb slice, frag order: [4 ftl][16 dt][64 lane][8]
    short* As = (short*)(lds + 65536);     // prototype staging (8 KB), XOR-swizzled
    short* Sb = (short*)(lds + 65536);     // epilogue bounce (after last As use)

    const int t = threadIdx.x;
    const int w = t >> 6, lane = t & 63, l15 = lane & 15, l4 = lane >> 4;
    const int rowg = blockIdx.x >> 2, nc = blockIdx.x & 3;
    const float alpha = *alpha_p, beta = *beta_p, theta = *theta_p;

    #pragma unroll
    for (int it = 0; it < 16; ++it) {
        int u = it * 256 + t;                       // 0..4095
        int ftl = u >> 10, dtl = (u >> 6) & 15, ln = u & 63;
        const float* src = features + (size_t)(nc * 128 + ftl * 32 + (ln & 31)) * Dsz
                         + dtl * 16 + (ln >> 5) * 8;
        float4v v0 = *(const float4v*)src;
        float4v v1 = *(const float4v*)(src + 4);
        uint4v uv;
        uv.x = cvt_pk_bf16(v0.x, v0.y);
        uv.y = cvt_pk_bf16(v0.z, v0.w);
        uv.z = cvt_pk_bf16(v1.x, v1.y);
        uv.w = cvt_pk_bf16(v1.z, v1.w);
        short8 sv = __builtin_bit_cast(short8, uv);
        *(short8*)&FB[u * 8] = sv;
        if (rowg == 0) {
            int go = (((nc * 4 + ftl) * 16 + dtl) * 64 + ln) * 8;
            *(short8*)&featbB[go] = sv;
        }
    }

    float4v acc[2][4];
    #pragma unroll
    for (int a = 0; a < 2; ++a)
        #pragma unroll
        for (int b = 0; b < 4; ++b) acc[a][b] = (float4v){0.f, 0.f, 0.f, 0.f};

    const float* pbase = prototypes + (size_t)rowg * 64 * Dsz;

    for (int kc = 0; kc < 4; ++kc) {
        __syncthreads();
        #pragma unroll
        for (int j = 0; j < 4; ++j) {
            int idx = j * 1024 + t * 4;
            int r = idx >> 6, c = idx & 63;
            float4v v = *(const float4v*)(pbase + (size_t)r * Dsz + kc * 64 + c);
            int unit = r * 8 + ((c >> 3) ^ (r & 7));
            short4v s4; s4.x = f2bf(v.x); s4.y = f2bf(v.y); s4.z = f2bf(v.z); s4.w = f2bf(v.w);
            *(short4v*)((char*)As + unit * 16 + (c & 7) * 2) = s4;
        }
        __syncthreads();
        #pragma unroll
        for (int kk = 0; kk < 2; ++kk) {
            short8 af[2], bfr[4];
            const int k8 = kk * 4 + l4;
            #pragma unroll
            for (int tm = 0; tm < 2; ++tm) {
                int m = (w & 1) * 32 + tm * 16 + l15;
                af[tm] = *(const short8*)&As[(m * 8 + (k8 ^ (m & 7))) * 8];
            }
            #pragma unroll
            for (int tn = 0; tn < 4; ++tn) {
                int fl = ((w >> 1) * 4 + tn) * 16 + l15;          // 0..127
                int dtl = kc * 4 + kk * 2 + (l4 >> 1);
                int lnp = (fl & 31) + 32 * (l4 & 1);
                bfr[tn] = *(const short8*)&FB[(((fl >> 5) * 16 + dtl) * 64 + lnp) * 8];
            }
            #pragma unroll
            for (int tm = 0; tm < 2; ++tm)
                #pragma unroll
                for (int tn = 0; tn < 4; ++tn)
                    acc[tm][tn] = __builtin_amdgcn_mfma_f32_16x16x32_bf16(af[tm], bfr[tn], acc[tm][tn], 0, 0, 0);
        }
    }
    __syncthreads();
    #pragma unroll
    for (int tm = 0; tm < 2; ++tm)
        #pragma unroll
        for (int tn = 0; tn < 4; ++tn)
            #pragma unroll
            for (int r = 0; r < 4; ++r) {
                int row = (w & 1) * 32 + tm * 16 + l4 * 4 + r;
                int col = (w >> 1) * 64 + tn * 16 + l15;
                Sb[row * SBPITCH + col] = f2bf(acc[tm][tn][r]);
            }
    __syncthreads();
    #pragma unroll
    for (int rep = 0; rep < 4; ++rep) {
        int u = rep * 256 + t;
        int row = u >> 4, i = u & 15;
        short8 sv = *(const short8*)&Sb[row * SBPITCH + i * 8];
        uint4v u0, u1;
        float sum = 0.f;
        #pragma unroll
        for (int e = 0; e < 8; ++e) {
            float pf = bf2f(sv[e]);
            float pp = fmaxf(pf, 0.f);
            float pw = pf * pp;
            float a0 = theta * pw + alpha * (pp - 1.f);   // multiplies xw
            float b0 = beta * pw;                          // multiplies xp
            sum += pw;
            unsigned pk = cvt_pk_bf16(a0, b0);
            if (e < 4) u0[e] = pk; else u1[e - 4] = pk;
        }
        int p = rowg * 64 + row;
        int c = 4 * nc + (i >> 2), s2 = i & 3, pt = p >> 5;
        int base = ((c * 4 + s2) * 8 + pt) * 512;
        *(short8*)&pab[base + (p & 31) * 8] = __builtin_bit_cast(short8, u0);
        *(short8*)&pab[base + ((p & 31) + 32) * 8] = __builtin_bit_cast(short8, u1);
        #pragma unroll
        for (int mk = 1; mk < 16; mk <<= 1) sum += __shfl_xor(sum, mk, 64);
        if (l15 == 0) pws_part[nc * 256 + p] = -beta * sum;
    }
}

// ---------------- k_main: K-split stage-1 dedup + pab direct-to-reg (T14) ----------------
// 1024 blocks x 256 thr (4 waves), 2 blocks/CU. Block: 64 m x 256 p.
// Wave (mt=w&1, pth=w>>1): stage-1 computes K-HALF (dt = pth*8..pth*8+7) of C1[32f][32m(mt)],
// exchanges f32 partials with pth-partner through lane-contiguous EXC (conflict-free),
// then stage-2 on its 128-p half with pab frags loaded global->reg in 2 batches (fenced).
// LDS 48 KB: FBL dbuf 2x16KB (gl_lds) + EXC 16KB.
__global__ __launch_bounds__(256, 2) void k_main(
    const float* __restrict__ x, const short* __restrict__ featbB,
    const short* __restrict__ pab, const float* __restrict__ pws_part,
    float* __restrict__ out)
{
    __shared__ short FBL[2][8192];   // fb dbuf: [buf][16 dt][lane*8]
    __shared__ float EXC[4096];      // 4 regions x 1024 f32 (lane-contiguous partials)

    const int t = threadIdx.x;
    const int w = t >> 6, lane = t & 63, l31 = lane & 31, h = lane >> 5;
    const int mt = w & 1, pth = w >> 1;
    const size_t row0 = (size_t)blockIdx.x * 64;
    const int lane8 = lane * 8;
    const int excW = (mt * 2 + pth) * 1024 + lane * 4;        // own region
    const int excR = (mt * 2 + (pth ^ 1)) * 1024 + lane * 4;  // partner region

    // fb chunk cn -> FBL[buf] (4 gl_lds per wave: tiles 4w..4w+3)
    auto stage_fb = [&](int cn, int buf) {
        const short* src = featbB + cn * 8192 + lane8;
        #pragma unroll
        for (int i = 0; i < 4; ++i)
            gl_lds16(src + (4 * w + i) * 512, &FBL[buf][(4 * w + i) * 512]);
    };

    // ---- prologue: stage fb(0); convert this wave's x K-half to 8 register frags ----
    stage_fb(0, 0);
    __builtin_amdgcn_sched_barrier(0);

    short8 xf[8];    // dt = pth*8 + i
    {
        const float* xr = x + (row0 + mt * 32 + l31) * Dsz + pth * 128 + h * 8;
        #pragma unroll
        for (int i = 0; i < 8; ++i) {
            float4v v0 = *(const float4v*)(xr + i * 16);
            float4v v1 = *(const float4v*)(xr + i * 16 + 4);
            uint4v uv;
            uv.x = cvt_pk_bf16(v0.x, v0.y);
            uv.y = cvt_pk_bf16(v0.z, v0.w);
            uv.z = cvt_pk_bf16(v1.x, v1.y);
            uv.w = cvt_pk_bf16(v1.z, v1.w);
            xf[i] = __builtin_bit_cast(short8, uv);
        }
    }

    float16v acc[4];
    #pragma unroll
    for (int a = 0; a < 4; ++a)
        #pragma unroll
        for (int e = 0; e < 16; ++e) acc[a][e] = 0.f;

    __syncthreads();                         // FBL[0] ready

    #pragma unroll 1
    for (int c = 0; c < 16; ++c) {
        const int cur = c & 1;

        if (c) __syncthreads();              // bar A: FBL[cur] ready, EXC free

        // ---- batch-A pab loads (s=0,1) straight to regs; covered by stage-1 ----
        const short* pb = pab + (size_t)c * 16384 + lane8;
        short8 PA[8];
        #pragma unroll
        for (int k = 0; k < 8; ++k)
            PA[k] = *(const short8*)(pb + ((k >> 2) * 8 + pth * 4 + (k & 3)) * 512);
        if (c < 15) stage_fb(c + 1, cur ^ 1);
        __builtin_amdgcn_sched_barrier(0);   // pin load issue above stage-1

        // ---- stage-1: K-half partial C1 (8 MFMA, 2 chains) ----
        float16v Ca, Cb;
        #pragma unroll
        for (int e = 0; e < 16; ++e) { Ca[e] = 0.f; Cb[e] = 0.f; }
        #pragma unroll
        for (int g = 0; g < 2; ++g) {
            short8 fbf[4];
            #pragma unroll
            for (int i = 0; i < 4; ++i)
                fbf[i] = *(const short8*)&FBL[cur][(pth * 8 + g * 4 + i) * 512 + lane8];
            __builtin_amdgcn_s_setprio(1);
            #pragma unroll
            for (int i = 0; i < 4; ++i) {
                if (i & 1) Cb = __builtin_amdgcn_mfma_f32_32x32x16_bf16(fbf[i], xf[g * 4 + i], Cb, 0, 0, 0);
                else       Ca = __builtin_amdgcn_mfma_f32_32x32x16_bf16(fbf[i], xf[g * 4 + i], Ca, 0, 0, 0);
            }
            __builtin_amdgcn_s_setprio(0);
        }
        float16v Cp;
        #pragma unroll
        for (int e = 0; e < 16; ++e) Cp[e] = Ca[e] + Cb[e];

        // ---- write own partial (lane-contiguous f32, conflict-free) ----
        #pragma unroll
        for (int q = 0; q < 4; ++q)
            *(float4v*)&EXC[excW + q * 256] =
                (float4v){Cp[4 * q], Cp[4 * q + 1], Cp[4 * q + 2], Cp[4 * q + 3]};

        __syncthreads();                     // bar B: partials visible (drains batch-A + gl_lds)

        // ---- batch-B pab loads (s=2,3); covered by merge + s=0,1 MFMAs ----
        short8 PB2[8];
        #pragma unroll
        for (int k = 0; k < 8; ++k)
            PB2[k] = *(const short8*)(pb + ((2 + (k >> 2)) * 8 + pth * 4 + (k & 3)) * 512);
        __builtin_amdgcn_sched_barrier(0);

        // ---- merge partner partial -> full C1 ----
        float16v C1;
        #pragma unroll
        for (int q = 0; q < 4; ++q) {
            float4v o = *(const float4v*)&EXC[excR + q * 256];
            C1[4 * q]     = Cp[4 * q]     + o.x;
            C1[4 * q + 1] = Cp[4 * q + 1] + o.y;
            C1[4 * q + 2] = Cp[4 * q + 2] + o.z;
            C1[4 * q + 3] = Cp[4 * q + 3] + o.w;
        }

        // ---- stage-2: per s repack + 4 MFMA into acc (pab frags in regs) ----
        #pragma unroll
        for (int s = 0; s < 4; ++s) {
            uint4v uf;
            #pragma unroll
            for (int q = 0; q < 4; ++q) {
                float xv = C1[4 * s + q];
                float xp = fmaxf(xv, 0.f);
                uf[q] = cvt_pk_bf16(xv * xp, xp);   // kappa even: xw, kappa odd: xp
            }
            short8 A2f = __builtin_bit_cast(short8, uf);
            __builtin_amdgcn_s_setprio(1);
            #pragma unroll
            for (int ptl = 0; ptl < 4; ++ptl) {
                short8 pfrag = (s < 2) ? PA[s * 4 + ptl] : PB2[(s - 2) * 4 + ptl];
                acc[ptl] = __builtin_amdgcn_mfma_f32_32x32x16_bf16(A2f, pfrag, acc[ptl], 0, 0, 0);
            }
            __builtin_amdgcn_s_setprio(0);
        }
    }

    // ---- epilogue: out[m][p] coalesced (p on lanes), + summed pws partials ----
    #pragma unroll
    for (int ptl = 0; ptl < 4; ++ptl) {
        int pcol = (pth * 4 + ptl) * 32 + l31;
        float pn = pws_part[pcol] + pws_part[256 + pcol] + pws_part[512 + pcol] + pws_part[768 + pcol];
        #pragma unroll
        for (int r = 0; r < 16; ++r) {
            size_t m = row0 + mt * 32 + (r & 3) + 8 * (r >> 2) + 4 * h;
            out[m * Psz + pcol] = acc[ptl][r] + pn;
        }
    }
}

// ---------------- launcher ----------------
extern "C" void kernel_launch(void* const* d_in, const int* in_sizes, int n_in,
                              void* d_out, int out_size, void* d_ws, size_t ws_size,
                              hipStream_t stream) {
    const float* x          = (const float*)d_in[0];
    const float* features   = (const float*)d_in[1];
    const float* prototypes = (const float*)d_in[2];
    const float* alpha      = (const float*)d_in[3];
    const float* beta       = (const float*)d_in[4];
    const float* theta      = (const float*)d_in[5];
    float* out = (float*)d_out;

    // ws: featbB 256KB @0, pab 512KB @262144, pws_part 4KB @786432
    char* ws = (char*)d_ws;
    short* featbB   = (short*)(ws);
    short* pab      = (short*)(ws + 262144);
    float* pws_part = (float*)(ws + 786432);

    hipLaunchKernelGGL(k_pre,  dim3(16),   dim3(256), 0, stream,
                       prototypes, features, alpha, beta, theta, featbB, pab, pws_part);
    hipLaunchKernelGGL(k_main, dim3(1024), dim3(256), 0, stream,
                       x, featbB, pab, pws_part, out);
}